// Round 5
// baseline (403.979 us; speedup 1.0000x reference)
//
#include <hip/hip_runtime.h>
#include <hip/hip_bf16.h>
#include <cstdint>
#include <cstddef>

// YatDense: out[m,n] = (y^2 / (|x_m|^2 + |w_n|^2 - 2y + eps)) * scale + bias[n]
//   y = x[m,:] . w[n,:]   GEMM M=16384, N=2048, K=2048 (B^T layout input)
// R9 = R8 with the LDS slot-overwrite race fixed. R8's failure: STAGE_A at
// p4/p8 overwrote a slot whose last ds_read was in the immediately-preceding
// phase (1 barrier). Cross-wave hazard: another wave's queued ds_read can be
// serviced AFTER the async DMA write lands -> reads next tile's data.
// Rule restored (R6/R7/m201 discipline): >=2 barriers between a slot's last
// read and its overwriting stage-issue.
//  - Stage placement per iter u (a=2u,b=2u+1):
//      p1: A(b)    [over A-odd, last read prev-p7: 2 bar; read p4, drain p3]
//      p2: B(a+2)  [over B-even, last read prev-p7: 3 bar; read p6, drain p5]
//      p5: A(a+2)  [over A-even, last read p3:      2 bar; read p8, drain p7]
//      p6: B(b+2)  [over B-odd,  last read p3:      3 bar; read next-p2,
//                                                   drain next-p1]
//    FIFO (4 loads/stage): entry [B(b)]; VM4 @p1 drains B(b); VM4 @p3 drains
//    A(b); VM4 @p5 drains B(a+2); VM4 @p7 drains A(a+2); exit [B(b+2)]. All
//    stage->first-read leashes 3-4 phases (>1800cy > 900cy HBM miss).
//  - Prologue: A(0),B(0),B(1) (12 loads), VM4 (leaves B(1)), SBAR, preloop.
//  - Peeled tail (tiles KT-2,KT-1): stage only A(KT-1)@p1; drains VM4@p1,
//    VM0@p3; stale pre-reads dropped.
//  - Extra SBAR between tile-0 epilogue and tile-1 stagepro (same 2-barrier
//    rule at the tile boundary).
//  - Kept from R8: hoisted ds_read/stage addressing (base+imm), persistent
//    pair-blocks (grid 256, bm=2q,2q+1 at fixed bn), pre-read double-buffer,
//    XOR swizzle, setprio around MFMA, sched_barrier(0), 1 barrier/phase.
// (Resubmitted unchanged after R4 infra timeout — never benched.)

typedef __bf16 bf16_t;
typedef __bf16 bf16x8 __attribute__((ext_vector_type(8)));
typedef __bf16 bf16x4 __attribute__((ext_vector_type(4)));
typedef float f32x4 __attribute__((ext_vector_type(4)));

constexpr int M_DIM = 16384;  // B*S
constexpr int N_DIM = 2048;   // F
constexpr int K_DIM = 2048;   // D
constexpr int BM = 256, BN = 256, BK = 64;
constexpr int KT = K_DIM / BK;  // 32 K-tiles
constexpr int SEG = 128 * 64;   // seg elements (16 KB)

__device__ __forceinline__ void async16(const bf16_t* g, bf16_t* l) {
    __builtin_amdgcn_global_load_lds(
        (const __attribute__((address_space(1))) void*)g,
        (__attribute__((address_space(3))) void*)l,
        16, 0, 0);
}

// ---------------------------------------------------------------------------
// prep: one WAVE per row; 8 rows per 256-thread block; grid 2304. (as R7)
// ---------------------------------------------------------------------------
__global__ __launch_bounds__(256) void prep_convert(const float* __restrict__ x,
                                                    const float* __restrict__ w,
                                                    bf16_t* __restrict__ xb,
                                                    bf16_t* __restrict__ wb,
                                                    float* __restrict__ xsq,
                                                    float* __restrict__ wsq) {
    const int lane = threadIdx.x & 63;
    const int wv = threadIdx.x >> 6;
    const int base = blockIdx.x * 8 + wv * 2;
#pragma unroll
    for (int it = 0; it < 2; ++it) {
        const int row = base + it;
        const float* src;
        bf16_t* dstb;
        float* dsts;
        if (row < M_DIM) {
            src = x + (size_t)row * K_DIM;
            dstb = xb + (size_t)row * K_DIM;
            dsts = xsq + row;
        } else {
            const int r = row - M_DIM;
            src = w + (size_t)r * K_DIM;
            dstb = wb + (size_t)r * K_DIM;
            dsts = wsq + r;
        }
        const float4* s4 = (const float4*)src;
        bf16x4* d4 = (bf16x4*)dstb;
        float s = 0.0f;
#pragma unroll
        for (int j = 0; j < 8; ++j) {
            const float4 a = s4[lane + j * 64];
            s += a.x * a.x + a.y * a.y + a.z * a.z + a.w * a.w;
            bf16x4 v = { (bf16_t)a.x, (bf16_t)a.y, (bf16_t)a.z, (bf16_t)a.w };
            d4[lane + j * 64] = v;
        }
#pragma unroll
        for (int off = 32; off > 0; off >>= 1) s += __shfl_down(s, off, 64);
        if (lane == 0) *dsts = s;
    }
}

// ---------------------------------------------------------------------------
// 8-phase pipelined GEMM + Yat epilogue, 2 output tiles per block.
// ---------------------------------------------------------------------------
__global__ __launch_bounds__(512, 2) void yat_gemm(const bf16_t* __restrict__ A,   // [M,K] bf16 (ws)
                                                   const bf16_t* __restrict__ Bw,  // [N,K] bf16 (ws)
                                                   const float* __restrict__ xsq,  // [M]
                                                   const float* __restrict__ wsq,  // [N]
                                                   const float* __restrict__ bias,   // [N] fp32
                                                   const float* __restrict__ alpha,  // [1] fp32
                                                   float* __restrict__ out) {        // [M,N] fp32
    __shared__ bf16_t sA[4 * SEG];  // 64 KB, ring of 4 A row-half segs
    __shared__ bf16_t sB[4 * SEG];  // 64 KB, ring of 4 B row-half segs

    const int tid = (int)threadIdx.x;
    const int lane = tid & 63;
    const int wv = tid >> 6;   // 0..7
    const int wm = wv >> 2;    // 0..1 : wave row (128-row band)
    const int wn = wv & 3;     // 0..3 : wave col (64-col band)

    const int bn = (int)blockIdx.x & 7;   // 0..7
    const int q = (int)blockIdx.x >> 3;   // 0..31
    const int bm0 = q * 2, bm1 = q * 2 + 1;

    // fragment addressing (mfma_f32_16x16x32_bf16):
    //  A: lane holds A[m=lane&15][k=(lane>>4)*8+j]; B mirrored ([n][k])
    //  C/D: col=lane&15, row=(lane>>4)*4+reg   [m89/m91-verified]
    const int frm = lane & 15;
    const int jch = lane >> 4;  // k-chunk 0..3 within a K=32 group
    const int sx = frm & 7;     // row-XOR for LDS swizzle

    // staging: thread t covers phys chunk (t&7) of seg row (t>>3) (+64 for
    // second load). LDS dest LINEAR (HW req); global source chunk is
    // inverse-permuted: g = (t&7) ^ (row&7).
    const int st_r = tid >> 3;  // 0..63
    const int st_g = (tid & 7) ^ (st_r & 7);
    const bf16_t* Bst = Bw + (size_t)(bn * BN + st_r) * K_DIM + st_g * 8;
    const bf16_t* Ast = A + (size_t)(bm0 * BM + st_r) * K_DIM + st_g * 8;

    // hoisted stage LDS destinations (one per ring slot)
    bf16_t* aSD[4];
    bf16_t* bSD[4];
#pragma unroll
    for (int s = 0; s < 4; ++s) {
        aSD[s] = sA + s * SEG + tid * 8;
        bSD[s] = sB + s * SEG + tid * 8;
    }

    // hoisted ds_read bases: [parity][kk]; all per-phase reads are base+imm.
    const bf16_t* aRB[2][2];
    const bf16_t* bRB[2][2];
#pragma unroll
    for (int p = 0; p < 2; ++p)
#pragma unroll
        for (int kk = 0; kk < 2; ++kk) {
            aRB[p][kk] = sA + (wm + 2 * p) * SEG + frm * BK + ((kk * 4 + jch) ^ sx) * 8;
            bRB[p][kk] = sB + ((wn >> 1) + 2 * p) * SEG + ((wn & 1) * 64 + frm) * BK
                         + ((kk * 4 + jch) ^ sx) * 8;
        }

    f32x4 acc[8][4] = {};
    bf16x8 afA[2][2], afB[2][2];    // [i2][kk] A frags, phase double-buffer
    bf16x8 bfrA[4][2], bfrB[4][2];  // [j][kk]  B frags, K-tile double-buffer

#define AF_READ(DST, PAR, QN)                                                  \
    _Pragma("unroll") for (int i2 = 0; i2 < 2; ++i2)                           \
        _Pragma("unroll") for (int kk = 0; kk < 2; ++kk)                       \
            DST[i2][kk] = *(const bf16x8*)(aRB[PAR][kk] + ((QN) * 2 + i2) * 1024);
#define BF_READ(DST, BJ0, PAR)                                                 \
    _Pragma("unroll") for (int jj = 0; jj < 2; ++jj)                           \
        _Pragma("unroll") for (int kk = 0; kk < 2; ++kk)                       \
            DST[(BJ0) + jj][kk] = *(const bf16x8*)(bRB[PAR][kk] + ((BJ0) + jj) * 1024);
#define MFMA16(QC, AFC, BFC)                                                   \
    __builtin_amdgcn_s_setprio(1);                                             \
    _Pragma("unroll") for (int kk = 0; kk < 2; ++kk)                           \
        _Pragma("unroll") for (int i2 = 0; i2 < 2; ++i2)                       \
            _Pragma("unroll") for (int j = 0; j < 4; ++j)                      \
                acc[(QC) * 2 + i2][j] = __builtin_amdgcn_mfma_f32_16x16x32_bf16( \
                    AFC[i2][kk], BFC[j][kk], acc[(QC) * 2 + i2][j], 0, 0, 0);  \
    __builtin_amdgcn_s_setprio(0);
#define SCHED0 __builtin_amdgcn_sched_barrier(0);
#define SBAR asm volatile("s_barrier" ::: "memory");
#define VM4 asm volatile("s_waitcnt vmcnt(4)" ::: "memory");
#define VM0 asm volatile("s_waitcnt vmcnt(0)" ::: "memory");
// stage: 4 loads covering one K-tile of A or B (slots are call-site literals)
#define STAGE_A(kt, S0, S1)                                                    \
    {                                                                          \
        const bf16_t* s_ = Ast + (size_t)(kt) * 64;                            \
        async16(s_, aSD[S0]);                                                  \
        async16(s_ + (size_t)64 * K_DIM, aSD[S0] + 4096);                      \
        async16(s_ + (size_t)128 * K_DIM, aSD[S1]);                            \
        async16(s_ + (size_t)192 * K_DIM, aSD[S1] + 4096);                     \
    }
#define STAGE_B(kt, S0, S1)                                                    \
    {                                                                          \
        const bf16_t* s_ = Bst + (size_t)(kt) * 64;                            \
        async16(s_, bSD[S0]);                                                  \
        async16(s_ + (size_t)64 * K_DIM, bSD[S0] + 4096);                      \
        async16(s_ + (size_t)128 * K_DIM, bSD[S1]);                            \
        async16(s_ + (size_t)192 * K_DIM, bSD[S1] + 4096);                     \
    }

    // prologue: A(0),B(0),B(1); VM4 drains A(0),B(0) (and any older stores),
    // leaves B(1) in flight -> matches steady-state entry FIFO [B(b)].
    auto stagepro = [&]() {
        STAGE_A(0, 0, 1)
        STAGE_B(0, 0, 1)
        STAGE_B(1, 2, 3)
    };
    auto preloop = [&]() {
        AF_READ(afA, 0, 0)
        BF_READ(bfrA, 0, 0)
        BF_READ(bfrA, 2, 0)
    };

    auto kloop = [&]() {
#pragma unroll 1
        for (int u = 0; u < KT / 2 - 1; ++u) {
            const int tb = 2 * u + 1, t2 = 2 * u + 2, t3 = 2 * u + 3;
            // p1: stage A(b)
            AF_READ(afB, 0, 1) STAGE_A(tb, 2, 3) SCHED0 MFMA16(0, afA, bfrA) VM4 SBAR
            // p2: stage B(a+2)
            AF_READ(afA, 0, 2) BF_READ(bfrB, 0, 1) STAGE_B(t2, 0, 1) SCHED0 MFMA16(1, afB, bfrA) SBAR
            // p3
            AF_READ(afB, 0, 3) BF_READ(bfrB, 2, 1) SCHED0 MFMA16(2, afA, bfrA) VM4 SBAR
            // p4
            AF_READ(afA, 1, 0) SCHED0 MFMA16(3, afB, bfrA) SBAR
            // p5: stage A(a+2)
            AF_READ(afB, 1, 1) STAGE_A(t2, 0, 1) SCHED0 MFMA16(0, afA, bfrB) VM4 SBAR
            // p6: stage B(b+2)
            AF_READ(afA, 1, 2) BF_READ(bfrA, 0, 0) STAGE_B(t3, 2, 3) SCHED0 MFMA16(1, afB, bfrB) SBAR
            // p7
            AF_READ(afB, 1, 3) BF_READ(bfrA, 2, 0) SCHED0 MFMA16(2, afA, bfrB) VM4 SBAR
            // p8
            AF_READ(afA, 0, 0) SCHED0 MFMA16(3, afB, bfrB) SBAR
        }
        // peeled tail (tiles KT-2, KT-1): stage only A(KT-1); drains VM4/VM0.
        AF_READ(afB, 0, 1) STAGE_A(KT - 1, 2, 3) SCHED0 MFMA16(0, afA, bfrA) VM4 SBAR
        AF_READ(afA, 0, 2) BF_READ(bfrB, 0, 1) SCHED0 MFMA16(1, afB, bfrA) SBAR
        AF_READ(afB, 0, 3) BF_READ(bfrB, 2, 1) SCHED0 MFMA16(2, afA, bfrA) VM0 SBAR
        AF_READ(afA, 1, 0) SCHED0 MFMA16(3, afB, bfrA) SBAR
        AF_READ(afB, 1, 1) SCHED0 MFMA16(0, afA, bfrB) SBAR
        AF_READ(afA, 1, 2) SCHED0 MFMA16(1, afB, bfrB) SBAR
        AF_READ(afB, 1, 3) SCHED0 MFMA16(2, afA, bfrB) SBAR
        SCHED0 MFMA16(3, afB, bfrB) SBAR
    };

    auto epilogue = [&](int bmv) {
        const float sc = powf(sqrtf((float)N_DIM) / logf(1.0f + (float)N_DIM), alpha[0]);
        float wsq_c[4], bias_c[4];
#pragma unroll
        for (int j = 0; j < 4; ++j) {
            const int col = bn * BN + wn * 64 + j * 16 + frm;
            wsq_c[j] = wsq[col];
            bias_c[j] = bias[col];
        }
#pragma unroll
        for (int i = 0; i < 8; ++i) {
#pragma unroll
            for (int r = 0; r < 4; ++r) {
                const int row = bmv * BM + wm * 128 + i * 16 + jch * 4 + r;
                const float xs = xsq[row];
                float* orow = out + (size_t)row * N_DIM + bn * BN + wn * 64 + frm;
#pragma unroll
                for (int j = 0; j < 4; ++j) {
                    const float y = acc[i][j][r];
                    const float d = xs + wsq_c[j] - 2.0f * y + 1e-6f;
                    orow[j * 16] = (y * y) / d * sc + bias_c[j];
                }
            }
        }
    };

    // ---- tile 0 (bm0) ----
    stagepro();
    VM4 SBAR
    preloop();
    kloop();
    epilogue(bm0);

    // ---- tile 1 (bm1): extra barrier enforces the 2-barrier rule between
    // tile-0's last ds_reads and stagepro's overwrites; prologue loads then
    // fly while the store queue drains. ----
    SBAR
    Ast = A + (size_t)(bm1 * BM + st_r) * K_DIM + st_g * 8;
    stagepro();
    VM4 SBAR
    preloop();
#pragma unroll
    for (int i = 0; i < 8; ++i)
#pragma unroll
        for (int j = 0; j < 4; ++j) {
            const f32x4 z = {};
            acc[i][j] = z;
        }
    kloop();
    epilogue(bm1);

#undef AF_READ
#undef BF_READ
#undef MFMA16
#undef SCHED0
#undef SBAR
#undef VM4
#undef VM0
#undef STAGE_A
#undef STAGE_B
}

extern "C" void kernel_launch(void* const* d_in, const int* in_sizes, int n_in,
                              void* d_out, int out_size, void* d_ws, size_t ws_size,
                              hipStream_t stream) {
    (void)in_sizes; (void)n_in; (void)out_size; (void)ws_size;
    const float* x = (const float*)d_in[0];      // [16384, 2048] fp32
    const float* w = (const float*)d_in[1];      // [2048, 2048] fp32
    const float* alpha = (const float*)d_in[2];  // [1] fp32
    const float* bias = (const float*)d_in[3];   // [2048] fp32
    float* out = (float*)d_out;                  // [16384, 2048] fp32

    // ws layout: xb (33.5M bf16), wb (4.2M bf16), xsq (16384 f32), wsq (2048 f32)
    bf16_t* xb = (bf16_t*)d_ws;
    bf16_t* wb = xb + (size_t)M_DIM * K_DIM;
    float* xsq = (float*)(wb + (size_t)N_DIM * K_DIM);
    float* wsq = xsq + M_DIM;

    prep_convert<<<(M_DIM + N_DIM) / 8, 256, 0, stream>>>(x, w, xb, wb, xsq, wsq);
    yat_gemm<<<(M_DIM / BM) * (N_DIM / BN) / 2, 512, 0, stream>>>(xb, wb, xsq, wsq, bias, alpha, out);
}

// Round 6
// 400.603 us; speedup vs baseline: 1.0084x; 1.0084x over previous
//
#include <hip/hip_runtime.h>
#include <hip/hip_bf16.h>
#include <cstdint>
#include <cstddef>

// YatDense: out[m,n] = (y^2 / (|x_m|^2 + |w_n|^2 - 2y + eps)) * scale + bias[n]
//   y = x[m,:] . w[n,:]   GEMM M=16384, N=2048, K=2048 (B^T layout input)
// R10 = R9 minus pair-blocks (A/B isolate). R9 regressed 144->181us with
// MfmaUtil 42->31.5% while VALUBusy dropped 29->21 (hoisting worked). The
// remaining R9 variable vs R7 is the grid-256 two-tile persistent block:
// chip-wide phase alignment (every CU stages/stores in sync, no second block
// population to interleave) + tile-boundary VM4 behind the full store queue.
// Revert to grid 512, one 256x256 tile/block; keep everything else from R9:
//  - 8-phase pipelined k-loop, pre-read double-buffer (afA/afB, bfrA/bfrB)
//  - stage placement p1:A(b) p2:B(a+2) p5:A(a+2) p6:B(b+2); VM4 @p1/p3/p5/p7
//    FIFO ledger: entry [B(b)]; p1 drains B(b) (read p2); p3 drains A(b)
//    (read p4); p5 drains B(a+2) (read p6); p7 drains A(a+2) (read p8).
//    >=2 barriers between any slot's last read and its overwriting stage.
//  - peeled tail stages A(KT-1) at tail-p1 (drained by tail-p3 VM0).
//  - hoisted ds_read/stage addressing (base+imm), XOR swizzle (conflicts 0),
//    setprio(1) around MFMA, sched_barrier(0) pin, 1 barrier/phase.

typedef __bf16 bf16_t;
typedef __bf16 bf16x8 __attribute__((ext_vector_type(8)));
typedef __bf16 bf16x4 __attribute__((ext_vector_type(4)));
typedef float f32x4 __attribute__((ext_vector_type(4)));

constexpr int M_DIM = 16384;  // B*S
constexpr int N_DIM = 2048;   // F
constexpr int K_DIM = 2048;   // D
constexpr int BM = 256, BN = 256, BK = 64;
constexpr int KT = K_DIM / BK;  // 32 K-tiles
constexpr int SEG = 128 * 64;   // seg elements (16 KB)

__device__ __forceinline__ void async16(const bf16_t* g, bf16_t* l) {
    __builtin_amdgcn_global_load_lds(
        (const __attribute__((address_space(1))) void*)g,
        (__attribute__((address_space(3))) void*)l,
        16, 0, 0);
}

// ---------------------------------------------------------------------------
// prep: one WAVE per row; 8 rows per 256-thread block; grid 2304. (as R7)
// ---------------------------------------------------------------------------
__global__ __launch_bounds__(256) void prep_convert(const float* __restrict__ x,
                                                    const float* __restrict__ w,
                                                    bf16_t* __restrict__ xb,
                                                    bf16_t* __restrict__ wb,
                                                    float* __restrict__ xsq,
                                                    float* __restrict__ wsq) {
    const int lane = threadIdx.x & 63;
    const int wv = threadIdx.x >> 6;
    const int base = blockIdx.x * 8 + wv * 2;
#pragma unroll
    for (int it = 0; it < 2; ++it) {
        const int row = base + it;
        const float* src;
        bf16_t* dstb;
        float* dsts;
        if (row < M_DIM) {
            src = x + (size_t)row * K_DIM;
            dstb = xb + (size_t)row * K_DIM;
            dsts = xsq + row;
        } else {
            const int r = row - M_DIM;
            src = w + (size_t)r * K_DIM;
            dstb = wb + (size_t)r * K_DIM;
            dsts = wsq + r;
        }
        const float4* s4 = (const float4*)src;
        bf16x4* d4 = (bf16x4*)dstb;
        float s = 0.0f;
#pragma unroll
        for (int j = 0; j < 8; ++j) {
            const float4 a = s4[lane + j * 64];
            s += a.x * a.x + a.y * a.y + a.z * a.z + a.w * a.w;
            bf16x4 v = { (bf16_t)a.x, (bf16_t)a.y, (bf16_t)a.z, (bf16_t)a.w };
            d4[lane + j * 64] = v;
        }
#pragma unroll
        for (int off = 32; off > 0; off >>= 1) s += __shfl_down(s, off, 64);
        if (lane == 0) *dsts = s;
    }
}

// ---------------------------------------------------------------------------
// 8-phase pipelined GEMM + Yat epilogue, one 256x256 tile per block.
// ---------------------------------------------------------------------------
__global__ __launch_bounds__(512, 2) void yat_gemm(const bf16_t* __restrict__ A,   // [M,K] bf16 (ws)
                                                   const bf16_t* __restrict__ Bw,  // [N,K] bf16 (ws)
                                                   const float* __restrict__ xsq,  // [M]
                                                   const float* __restrict__ wsq,  // [N]
                                                   const float* __restrict__ bias,   // [N] fp32
                                                   const float* __restrict__ alpha,  // [1] fp32
                                                   float* __restrict__ out) {        // [M,N] fp32
    __shared__ bf16_t sA[4 * SEG];  // 64 KB, ring of 4 A row-half segs
    __shared__ bf16_t sB[4 * SEG];  // 64 KB, ring of 4 B row-half segs

    const int tid = (int)threadIdx.x;
    const int lane = tid & 63;
    const int wv = tid >> 6;   // 0..7
    const int wm = wv >> 2;    // 0..1 : wave row (128-row band)
    const int wn = wv & 3;     // 0..3 : wave col (64-col band)

    const int bm = (int)blockIdx.x >> 3;  // 0..63
    const int bn = (int)blockIdx.x & 7;   // 0..7

    // fragment addressing (mfma_f32_16x16x32_bf16):
    //  A: lane holds A[m=lane&15][k=(lane>>4)*8+j]; B mirrored ([n][k])
    //  C/D: col=lane&15, row=(lane>>4)*4+reg   [m89/m91-verified]
    const int frm = lane & 15;
    const int jch = lane >> 4;  // k-chunk 0..3 within a K=32 group
    const int sx = frm & 7;     // row-XOR for LDS swizzle

    // staging: thread t covers phys chunk (t&7) of seg row (t>>3) (+64 for
    // second load). LDS dest LINEAR (HW req); global source chunk is
    // inverse-permuted: g = (t&7) ^ (row&7).
    const int st_r = tid >> 3;  // 0..63
    const int st_g = (tid & 7) ^ (st_r & 7);
    const bf16_t* Bst = Bw + (size_t)(bn * BN + st_r) * K_DIM + st_g * 8;
    const bf16_t* Ast = A + (size_t)(bm * BM + st_r) * K_DIM + st_g * 8;

    // hoisted stage LDS destinations (one per ring slot)
    bf16_t* aSD[4];
    bf16_t* bSD[4];
#pragma unroll
    for (int s = 0; s < 4; ++s) {
        aSD[s] = sA + s * SEG + tid * 8;
        bSD[s] = sB + s * SEG + tid * 8;
    }

    // hoisted ds_read bases: [parity][kk]; all per-phase reads are base+imm.
    const bf16_t* aRB[2][2];
    const bf16_t* bRB[2][2];
#pragma unroll
    for (int p = 0; p < 2; ++p)
#pragma unroll
        for (int kk = 0; kk < 2; ++kk) {
            aRB[p][kk] = sA + (wm + 2 * p) * SEG + frm * BK + ((kk * 4 + jch) ^ sx) * 8;
            bRB[p][kk] = sB + ((wn >> 1) + 2 * p) * SEG + ((wn & 1) * 64 + frm) * BK
                         + ((kk * 4 + jch) ^ sx) * 8;
        }

    f32x4 acc[8][4] = {};
    bf16x8 afA[2][2], afB[2][2];    // [i2][kk] A frags, phase double-buffer
    bf16x8 bfrA[4][2], bfrB[4][2];  // [j][kk]  B frags, K-tile double-buffer

#define AF_READ(DST, PAR, QN)                                                  \
    _Pragma("unroll") for (int i2 = 0; i2 < 2; ++i2)                           \
        _Pragma("unroll") for (int kk = 0; kk < 2; ++kk)                       \
            DST[i2][kk] = *(const bf16x8*)(aRB[PAR][kk] + ((QN) * 2 + i2) * 1024);
#define BF_READ(DST, BJ0, PAR)                                                 \
    _Pragma("unroll") for (int jj = 0; jj < 2; ++jj)                           \
        _Pragma("unroll") for (int kk = 0; kk < 2; ++kk)                       \
            DST[(BJ0) + jj][kk] = *(const bf16x8*)(bRB[PAR][kk] + ((BJ0) + jj) * 1024);
#define MFMA16(QC, AFC, BFC)                                                   \
    __builtin_amdgcn_s_setprio(1);                                             \
    _Pragma("unroll") for (int kk = 0; kk < 2; ++kk)                           \
        _Pragma("unroll") for (int i2 = 0; i2 < 2; ++i2)                       \
            _Pragma("unroll") for (int j = 0; j < 4; ++j)                      \
                acc[(QC) * 2 + i2][j] = __builtin_amdgcn_mfma_f32_16x16x32_bf16( \
                    AFC[i2][kk], BFC[j][kk], acc[(QC) * 2 + i2][j], 0, 0, 0);  \
    __builtin_amdgcn_s_setprio(0);
#define SCHED0 __builtin_amdgcn_sched_barrier(0);
#define SBAR asm volatile("s_barrier" ::: "memory");
#define VM4 asm volatile("s_waitcnt vmcnt(4)" ::: "memory");
#define VM0 asm volatile("s_waitcnt vmcnt(0)" ::: "memory");
// stage: 4 loads covering one K-tile of A or B (slots are call-site literals)
#define STAGE_A(kt, S0, S1)                                                    \
    {                                                                          \
        const bf16_t* s_ = Ast + (size_t)(kt) * 64;                            \
        async16(s_, aSD[S0]);                                                  \
        async16(s_ + (size_t)64 * K_DIM, aSD[S0] + 4096);                      \
        async16(s_ + (size_t)128 * K_DIM, aSD[S1]);                            \
        async16(s_ + (size_t)192 * K_DIM, aSD[S1] + 4096);                     \
    }
#define STAGE_B(kt, S0, S1)                                                    \
    {                                                                          \
        const bf16_t* s_ = Bst + (size_t)(kt) * 64;                            \
        async16(s_, bSD[S0]);                                                  \
        async16(s_ + (size_t)64 * K_DIM, bSD[S0] + 4096);                      \
        async16(s_ + (size_t)128 * K_DIM, bSD[S1]);                            \
        async16(s_ + (size_t)192 * K_DIM, bSD[S1] + 4096);                     \
    }

    // prologue: A(0),B(0),B(1); VM4 drains A(0),B(0), leaves B(1) in flight
    // -> matches steady-state entry FIFO [B(b)].
    STAGE_A(0, 0, 1)
    STAGE_B(0, 0, 1)
    STAGE_B(1, 2, 3)
    VM4 SBAR
    AF_READ(afA, 0, 0)
    BF_READ(bfrA, 0, 0)
    BF_READ(bfrA, 2, 0)

#pragma unroll 1
    for (int u = 0; u < KT / 2 - 1; ++u) {
        const int tb = 2 * u + 1, t2 = 2 * u + 2, t3 = 2 * u + 3;
        // p1: stage A(b)
        AF_READ(afB, 0, 1) STAGE_A(tb, 2, 3) SCHED0 MFMA16(0, afA, bfrA) VM4 SBAR
        // p2: stage B(a+2)
        AF_READ(afA, 0, 2) BF_READ(bfrB, 0, 1) STAGE_B(t2, 0, 1) SCHED0 MFMA16(1, afB, bfrA) SBAR
        // p3
        AF_READ(afB, 0, 3) BF_READ(bfrB, 2, 1) SCHED0 MFMA16(2, afA, bfrA) VM4 SBAR
        // p4
        AF_READ(afA, 1, 0) SCHED0 MFMA16(3, afB, bfrA) SBAR
        // p5: stage A(a+2)
        AF_READ(afB, 1, 1) STAGE_A(t2, 0, 1) SCHED0 MFMA16(0, afA, bfrB) VM4 SBAR
        // p6: stage B(b+2)
        AF_READ(afA, 1, 2) BF_READ(bfrA, 0, 0) STAGE_B(t3, 2, 3) SCHED0 MFMA16(1, afB, bfrB) SBAR
        // p7
        AF_READ(afB, 1, 3) BF_READ(bfrA, 2, 0) SCHED0 MFMA16(2, afA, bfrB) VM4 SBAR
        // p8
        AF_READ(afA, 0, 0) SCHED0 MFMA16(3, afB, bfrB) SBAR
    }
    // peeled tail (tiles KT-2, KT-1): stage only A(KT-1); drains VM4/VM0.
    AF_READ(afB, 0, 1) STAGE_A(KT - 1, 2, 3) SCHED0 MFMA16(0, afA, bfrA) VM4 SBAR
    AF_READ(afA, 0, 2) BF_READ(bfrB, 0, 1) SCHED0 MFMA16(1, afB, bfrA) SBAR
    AF_READ(afB, 0, 3) BF_READ(bfrB, 2, 1) SCHED0 MFMA16(2, afA, bfrA) VM0 SBAR
    AF_READ(afA, 1, 0) SCHED0 MFMA16(3, afB, bfrA) SBAR
    AF_READ(afB, 1, 1) SCHED0 MFMA16(0, afA, bfrB) SBAR
    AF_READ(afA, 1, 2) SCHED0 MFMA16(1, afB, bfrB) SBAR
    AF_READ(afB, 1, 3) SCHED0 MFMA16(2, afA, bfrB) SBAR
    SCHED0 MFMA16(3, afB, bfrB) SBAR

    // epilogue (fp32 stores)
    const float sc = powf(sqrtf((float)N_DIM) / logf(1.0f + (float)N_DIM), alpha[0]);
    float wsq_c[4], bias_c[4];
#pragma unroll
    for (int j = 0; j < 4; ++j) {
        const int col = bn * BN + wn * 64 + j * 16 + frm;
        wsq_c[j] = wsq[col];
        bias_c[j] = bias[col];
    }
#pragma unroll
    for (int i = 0; i < 8; ++i) {
#pragma unroll
        for (int r = 0; r < 4; ++r) {
            const int row = bm * BM + wm * 128 + i * 16 + jch * 4 + r;
            const float xs = xsq[row];
            float* orow = out + (size_t)row * N_DIM + bn * BN + wn * 64 + frm;
#pragma unroll
            for (int j = 0; j < 4; ++j) {
                const float y = acc[i][j][r];
                const float d = xs + wsq_c[j] - 2.0f * y + 1e-6f;
                orow[j * 16] = (y * y) / d * sc + bias_c[j];
            }
        }
    }

#undef AF_READ
#undef BF_READ
#undef MFMA16
#undef SCHED0
#undef SBAR
#undef VM4
#undef VM0
#undef STAGE_A
#undef STAGE_B
}

extern "C" void kernel_launch(void* const* d_in, const int* in_sizes, int n_in,
                              void* d_out, int out_size, void* d_ws, size_t ws_size,
                              hipStream_t stream) {
    (void)in_sizes; (void)n_in; (void)out_size; (void)ws_size;
    const float* x = (const float*)d_in[0];      // [16384, 2048] fp32
    const float* w = (const float*)d_in[1];      // [2048, 2048] fp32
    const float* alpha = (const float*)d_in[2];  // [1] fp32
    const float* bias = (const float*)d_in[3];   // [2048] fp32
    float* out = (float*)d_out;                  // [16384, 2048] fp32

    // ws layout: xb (33.5M bf16), wb (4.2M bf16), xsq (16384 f32), wsq (2048 f32)
    bf16_t* xb = (bf16_t*)d_ws;
    bf16_t* wb = xb + (size_t)M_DIM * K_DIM;
    float* xsq = (float*)(wb + (size_t)N_DIM * K_DIM);
    float* wsq = xsq + M_DIM;

    prep_convert<<<(M_DIM + N_DIM) / 8, 256, 0, stream>>>(x, w, xb, wb, xsq, wsq);
    yat_gemm<<<(M_DIM / BM) * (N_DIM / BN), 512, 0, stream>>>(xb, wb, xsq, wsq, bias, alpha, out);
}

// Round 7
// 371.207 us; speedup vs baseline: 1.0883x; 1.0792x over previous
//
#include <hip/hip_runtime.h>
#include <hip/hip_bf16.h>
#include <cstdint>
#include <cstddef>

// YatDense: out[m,n] = (y^2 / (|x_m|^2 + |w_n|^2 - 2y + eps)) * scale + bias[n]
//   y = x[m,:] . w[n,:]   GEMM M=16384, N=2048, K=2048 (B^T layout input)
// R11 = R7 (best verified: gemm 144us) + ONE change: XCD-chunked block
// swizzle. Evidence: FETCH=272MB vs ~75MB ideal (A-panel fetched ~4x because
// its 8 bn-sibling blocks land on 8 different XCDs under round-robin
// dispatch). Map p -> (xcd=p&7, s=p>>3, bm=xcd*8+s/8, bn=s%8): bn-siblings
// become temporally adjacent on ONE XCD -> single L2 fill per A panel; VM4
// drains then wait on L2/L3 hits (~200cy) not HBM misses (~900cy).
// R9/R10 lesson recorded: hoisted addressing + B-stage clustering + peeled
// tail REGRESSED (173us, MfmaUtil 32%) despite lower VALUBusy — reverted
// wholesale to R7's schedule:
//  - 8-phase pipelined k-loop, pre-read double-buffer (afA/afB, bfrA/bfrB)
//  - stages p1:A(b) p2:B(a+2,0) p3:B(a+2,1) p5:A(a+2) p6:B(b+2,0) p7:B(b+2,1)
//  - VM4 at p1/p3/p5/p7 (FIFO ledger verified); vmcnt(0) fallback on tail
//  - XOR LDS swizzle (conflicts 0), setprio(1) around MFMA, sched_barrier(0),
//    1 barrier/phase, grid 512, one 256x256 tile per block.

typedef __bf16 bf16_t;
typedef __bf16 bf16x8 __attribute__((ext_vector_type(8)));
typedef __bf16 bf16x4 __attribute__((ext_vector_type(4)));
typedef float f32x4 __attribute__((ext_vector_type(4)));

constexpr int M_DIM = 16384;  // B*S
constexpr int N_DIM = 2048;   // F
constexpr int K_DIM = 2048;   // D
constexpr int BM = 256, BN = 256, BK = 64;
constexpr int KT = K_DIM / BK;  // 32 K-tiles
constexpr int SEG = 128 * 64;   // seg elements (16 KB)

__device__ __forceinline__ void async16(const bf16_t* g, bf16_t* l) {
    __builtin_amdgcn_global_load_lds(
        (const __attribute__((address_space(1))) void*)g,
        (__attribute__((address_space(3))) void*)l,
        16, 0, 0);
}

// ---------------------------------------------------------------------------
// prep: one WAVE per row; 8 rows per 256-thread block; grid 2304. (as R7)
// ---------------------------------------------------------------------------
__global__ __launch_bounds__(256) void prep_convert(const float* __restrict__ x,
                                                    const float* __restrict__ w,
                                                    bf16_t* __restrict__ xb,
                                                    bf16_t* __restrict__ wb,
                                                    float* __restrict__ xsq,
                                                    float* __restrict__ wsq) {
    const int lane = threadIdx.x & 63;
    const int wv = threadIdx.x >> 6;
    const int base = blockIdx.x * 8 + wv * 2;
#pragma unroll
    for (int it = 0; it < 2; ++it) {
        const int row = base + it;
        const float* src;
        bf16_t* dstb;
        float* dsts;
        if (row < M_DIM) {
            src = x + (size_t)row * K_DIM;
            dstb = xb + (size_t)row * K_DIM;
            dsts = xsq + row;
        } else {
            const int r = row - M_DIM;
            src = w + (size_t)r * K_DIM;
            dstb = wb + (size_t)r * K_DIM;
            dsts = wsq + r;
        }
        const float4* s4 = (const float4*)src;
        bf16x4* d4 = (bf16x4*)dstb;
        float s = 0.0f;
#pragma unroll
        for (int j = 0; j < 8; ++j) {
            const float4 a = s4[lane + j * 64];
            s += a.x * a.x + a.y * a.y + a.z * a.z + a.w * a.w;
            bf16x4 v = { (bf16_t)a.x, (bf16_t)a.y, (bf16_t)a.z, (bf16_t)a.w };
            d4[lane + j * 64] = v;
        }
#pragma unroll
        for (int off = 32; off > 0; off >>= 1) s += __shfl_down(s, off, 64);
        if (lane == 0) *dsts = s;
    }
}

// ---------------------------------------------------------------------------
// 8-phase pipelined GEMM + Yat epilogue. (R7 schedule verbatim)
// ---------------------------------------------------------------------------
__global__ __launch_bounds__(512, 2) void yat_gemm(const bf16_t* __restrict__ A,   // [M,K] bf16 (ws)
                                                   const bf16_t* __restrict__ Bw,  // [N,K] bf16 (ws)
                                                   const float* __restrict__ xsq,  // [M]
                                                   const float* __restrict__ wsq,  // [N]
                                                   const float* __restrict__ bias,   // [N] fp32
                                                   const float* __restrict__ alpha,  // [1] fp32
                                                   float* __restrict__ out) {        // [M,N] fp32
    __shared__ bf16_t sA[4 * SEG];  // 64 KB, ring of 4 A row-half segs
    __shared__ bf16_t sB[4 * SEG];  // 64 KB, ring of 4 B row-half segs

    const int tid = (int)threadIdx.x;
    const int lane = tid & 63;
    const int wv = tid >> 6;   // 0..7
    const int wm = wv >> 2;    // 0..1 : wave row (128-row band)
    const int wn = wv & 3;     // 0..3 : wave col (64-col band)

    // XCD-chunked swizzle (R11): round-robin dispatch puts blockIdx p on XCD
    // p&7; give XCD x the contiguous bm-range [x*8, x*8+8), bn fastest, so
    // the 8 blocks sharing an A panel are temporally adjacent on one XCD.
    const int p = (int)blockIdx.x;
    const int s_ord = p >> 3;                    // 0..63 temporal order on XCD
    const int bm = (p & 7) * 8 + (s_ord >> 3);   // 0..63
    const int bn = s_ord & 7;                    // 0..7

    // fragment addressing (mfma_f32_16x16x32_bf16):
    //  A: lane holds A[m=lane&15][k=(lane>>4)*8+j]; B mirrored ([n][k])
    //  C/D: col=lane&15, row=(lane>>4)*4+reg   [m89/m91-verified]
    const int frm = lane & 15;
    const int jch = lane >> 4;  // k-chunk 0..3 within a K=32 group
    const int sx = frm & 7;     // row-XOR for LDS swizzle

    // staging: thread t covers phys chunk (t&7) of seg row (t>>3) (+64 for
    // second load). LDS dest LINEAR (HW req); global source chunk is
    // inverse-permuted: g = (t&7) ^ (row&7).
    const int st_r = tid >> 3;  // 0..63
    const int st_g = (tid & 7) ^ (st_r & 7);
    const bf16_t* Ast = A + (size_t)(bm * BM + st_r) * K_DIM + st_g * 8;
    const bf16_t* Bst = Bw + (size_t)(bn * BN + st_r) * K_DIM + st_g * 8;

    auto stageA2 = [&](int kt) {  // both halves of A K-tile kt (4 loads)
        if (kt >= KT) return;
#pragma unroll
        for (int h = 0; h < 2; ++h) {
            bf16_t* d = sA + ((kt * 2 + h) & 3) * SEG + tid * 8;
            const bf16_t* s = Ast + (size_t)(h * 128) * K_DIM + kt * 64;
            async16(s, d);
            async16(s + (size_t)64 * K_DIM, d + 4096);
        }
    };
    auto stageB1 = [&](int kt, int h) {  // one half of B K-tile kt (2 loads)
        if (kt >= KT) return;
        bf16_t* d = sB + ((kt * 2 + h) & 3) * SEG + tid * 8;
        const bf16_t* s = Bst + (size_t)(h * 128) * K_DIM + kt * 64;
        async16(s, d);
        async16(s + (size_t)64 * K_DIM, d + 4096);
    };

    f32x4 acc[8][4] = {};
    bf16x8 afA[2][2], afB[2][2];    // [i2][kk] A frags, phase double-buffer
    bf16x8 bfrA[4][2], bfrB[4][2];  // [j][kk]  B frags, K-tile double-buffer

#define AF_READ(DST, KTN, QN)                                                  \
    {                                                                          \
        const int aslot_ = (((KTN) * 2 + wm) & 3) * SEG;                       \
        _Pragma("unroll") for (int i2 = 0; i2 < 2; ++i2)                       \
            _Pragma("unroll") for (int kk = 0; kk < 2; ++kk)                   \
                DST[i2][kk] = *(const bf16x8*)&sA[aslot_ +                     \
                    (((QN) * 2 + i2) * 16 + frm) * 64 + (((kk * 4 + jch) ^ sx) * 8)]; \
    }
#define BF_READ(DST, BJ0, KTB)                                                 \
    {                                                                          \
        const int bslot_ = (((KTB) * 2 + (wn >> 1)) & 3) * SEG;                \
        _Pragma("unroll") for (int jj = 0; jj < 2; ++jj)                       \
            _Pragma("unroll") for (int kk = 0; kk < 2; ++kk)                   \
                DST[(BJ0) + jj][kk] = *(const bf16x8*)&sB[bslot_ +             \
                    ((wn & 1) * 64 + ((BJ0) + jj) * 16 + frm) * 64 +           \
                    (((kk * 4 + jch) ^ sx) * 8)];                              \
    }
#define MFMA16(QC, AFC, BFC)                                                   \
    __builtin_amdgcn_s_setprio(1);                                             \
    _Pragma("unroll") for (int kk = 0; kk < 2; ++kk)                           \
        _Pragma("unroll") for (int i2 = 0; i2 < 2; ++i2)                       \
            _Pragma("unroll") for (int j = 0; j < 4; ++j)                      \
                acc[(QC) * 2 + i2][j] = __builtin_amdgcn_mfma_f32_16x16x32_bf16( \
                    AFC[i2][kk], BFC[j][kk], acc[(QC) * 2 + i2][j], 0, 0, 0);  \
    __builtin_amdgcn_s_setprio(0);
#define SCHED0 __builtin_amdgcn_sched_barrier(0);
#define SBAR asm volatile("s_barrier" ::: "memory");
#define VMC4 asm volatile("s_waitcnt vmcnt(4)" ::: "memory");
#define VMC(SKT)                                                               \
    if ((SKT) < KT) { VMC4 } else { asm volatile("s_waitcnt vmcnt(0)" ::: "memory"); }

    // prologue: A(0), B(0), B(1) staged; drain A(0),B(0) (keep B(1) in
    // flight); read tile-0 frags (afA Q0 + bfrA).
    stageA2(0);
    stageB1(0, 0); stageB1(0, 1);
    stageB1(1, 0); stageB1(1, 1);
    VMC4
    SBAR
    AF_READ(afA, 0, 0)
    BF_READ(bfrA, 0, 0)
    BF_READ(bfrA, 2, 0)

#pragma unroll 1
    for (int u = 0; u < KT / 2; ++u) {
        const int a = 2 * u, b = a + 1;
        // p1: compute (a,Q0); pre-read (a,Q1); stage A(b)
        AF_READ(afB, a, 1)
        stageA2(b);
        SCHED0
        MFMA16(0, afA, bfrA)
        VMC4            // keep A(b); drains B(b) [staged prev p6/p7] for p2
        SBAR
        // p2: compute (a,Q1); pre-read (a,Q2) + bfr(b) lo; stage B(a+2,0)
        AF_READ(afA, a, 2)
        BF_READ(bfrB, 0, b)
        stageB1(a + 2, 0);
        SCHED0
        MFMA16(1, afB, bfrA)
        SBAR
        // p3: compute (a,Q2); pre-read (a,Q3) + bfr(b) hi; stage B(a+2,1)
        AF_READ(afB, a, 3)
        BF_READ(bfrB, 2, b)
        stageB1(a + 2, 1);
        SCHED0
        MFMA16(2, afA, bfrA)
        VMC(a + 2)      // keep B(a+2); drains A(b) for p4's pre-read
        SBAR
        // p4: compute (a,Q3); pre-read (b,Q0); no stage
        AF_READ(afA, b, 0)
        SCHED0
        MFMA16(3, afB, bfrA)
        SBAR
        // p5: compute (b,Q0); pre-read (b,Q1); stage A(a+2)
        AF_READ(afB, b, 1)
        stageA2(a + 2);
        SCHED0
        MFMA16(0, afA, bfrB)
        VMC(a + 2)      // keep A(a+2); drains B(a+2) for p6's bfr reads
        SBAR
        // p6: compute (b,Q1); pre-read (b,Q2) + bfr(a+2) lo; stage B(b+2,0)
        AF_READ(afA, b, 2)
        BF_READ(bfrA, 0, a + 2)
        stageB1(b + 2, 0);
        SCHED0
        MFMA16(1, afB, bfrB)
        SBAR
        // p7: compute (b,Q2); pre-read (b,Q3) + bfr(a+2) hi; stage B(b+2,1)
        AF_READ(afB, b, 3)
        BF_READ(bfrA, 2, a + 2)
        stageB1(b + 2, 1);
        SCHED0
        MFMA16(2, afA, bfrB)
        VMC(b + 2)      // keep B(b+2); drains A(a+2) for p8's pre-read
        SBAR
        // p8: compute (b,Q3); pre-read (a+2,Q0); no stage
        AF_READ(afA, a + 2, 0)
        SCHED0
        MFMA16(3, afB, bfrB)
        SBAR
    }
#undef AF_READ
#undef BF_READ
#undef MFMA16
#undef SCHED0
#undef SBAR
#undef VMC4
#undef VMC

    // epilogue (fp32 stores)
    const float sc = powf(sqrtf((float)N_DIM) / logf(1.0f + (float)N_DIM), alpha[0]);
    float wsq_c[4], bias_c[4];
#pragma unroll
    for (int j = 0; j < 4; ++j) {
        const int col = bn * BN + wn * 64 + j * 16 + frm;
        wsq_c[j] = wsq[col];
        bias_c[j] = bias[col];
    }
#pragma unroll
    for (int i = 0; i < 8; ++i) {
#pragma unroll
        for (int r = 0; r < 4; ++r) {
            const int row = bm * BM + wm * 128 + i * 16 + jch * 4 + r;
            const float xs = xsq[row];
            float* orow = out + (size_t)row * N_DIM + bn * BN + wn * 64 + frm;
#pragma unroll
            for (int j = 0; j < 4; ++j) {
                const float y = acc[i][j][r];
                const float d = xs + wsq_c[j] - 2.0f * y + 1e-6f;
                orow[j * 16] = (y * y) / d * sc + bias_c[j];
            }
        }
    }
}

extern "C" void kernel_launch(void* const* d_in, const int* in_sizes, int n_in,
                              void* d_out, int out_size, void* d_ws, size_t ws_size,
                              hipStream_t stream) {
    (void)in_sizes; (void)n_in; (void)out_size; (void)ws_size;
    const float* x = (const float*)d_in[0];      // [16384, 2048] fp32
    const float* w = (const float*)d_in[1];      // [2048, 2048] fp32
    const float* alpha = (const float*)d_in[2];  // [1] fp32
    const float* bias = (const float*)d_in[3];   // [2048] fp32
    float* out = (float*)d_out;                  // [16384, 2048] fp32

    // ws layout: xb (33.5M bf16), wb (4.2M bf16), xsq (16384 f32), wsq (2048 f32)
    bf16_t* xb = (bf16_t*)d_ws;
    bf16_t* wb = xb + (size_t)M_DIM * K_DIM;
    float* xsq = (float*)(wb + (size_t)N_DIM * K_DIM);
    float* wsq = xsq + M_DIM;

    prep_convert<<<(M_DIM + N_DIM) / 8, 256, 0, stream>>>(x, w, xb, wb, xsq, wsq);
    yat_gemm<<<(M_DIM / BM) * (N_DIM / BN), 512, 0, stream>>>(xb, wb, xsq, wsq, bias, alpha, out);
}